// Round 25
// baseline (64.077 us; speedup 1.0000x reference)
//
#include <hip/hip_runtime.h>

// EntityAttention — round 25: R24 with the compile error fixed (acc declared
// before the lambdas that capture it in outgf). Kill the P round-trip:
// pnorm -> sums (inv only); outgf = staged-B m97 pipeline + in-kernel A-build.
// NB=8 SL=512 NH=512 EN=16 NE=64 HEADS=2 DH=256.

#define NB 8
#define SL 512
#define NH 512
#define EN 16
#define NE 64
#define HEADS 2
#define DH 256
#define SCALE 0.0625f

typedef __attribute__((ext_vector_type(8))) short short8;
typedef __attribute__((ext_vector_type(4))) short short4v;
typedef __attribute__((ext_vector_type(4))) float f32x4;

#define MFMA16(a, b, c) __builtin_amdgcn_mfma_f32_16x16x32_bf16(a, b, c, 0, 0, 0)

__device__ __forceinline__ short f2b(float f) {
    unsigned u = __builtin_bit_cast(unsigned, f);
    u += 0x7fffu + ((u >> 16) & 1u);
    return (short)(u >> 16);
}
__device__ __forceinline__ float b2f(short s) {
    return __builtin_bit_cast(float, ((unsigned)(unsigned short)s) << 16);
}
__device__ __forceinline__ int swz8(int hw, int chunk) {
    return (hw & 7) * chunk + (hw >> 3);
}

// async global->LDS, 16B per lane; HW writes lane l at ldsbase + l*16.
__device__ __forceinline__ void gload16(const short* g, short* l) {
    __builtin_amdgcn_global_load_lds(
        (const __attribute__((address_space(1))) unsigned int*)g,
        (__attribute__((address_space(3))) unsigned int*)l, 16, 0, 0);
}

__device__ __forceinline__ void mm42(f32x4 (&acc)[4][2], const short8 (&a)[4], const short8 (&bb)[2]) {
#pragma unroll
    for (int i = 0; i < 4; ++i)
#pragma unroll
        for (int j = 0; j < 2; ++j) acc[i][j] = MFMA16(a[i], bb[j], acc[i][j]);
}
__device__ __forceinline__ void mm44(f32x4 (&acc)[4][4], const short8 (&a)[4], const short8 (&bb)[4]) {
#pragma unroll
    for (int i = 0; i < 4; ++i)
#pragma unroll
        for (int j = 0; j < 4; ++j) acc[i][j] = MFMA16(a[i], bb[j], acc[i][j]);
}

// ---- ws byte offsets -------------------------------------------------------
#define WS_TOKS 0u
#define WS_K (4u << 20)
#define WS_V (8u << 20)
#define WS_S (20u << 20)
#define WS_WK (22u << 20)
#define WS_WV (WS_WK + (512u << 10))
#define WS_WO (WS_WV + (512u << 10))
#define WS_WQ (WS_WO + (512u << 10))
#define WS_EV (WS_WQ + (512u << 10))
#define WS_Q (WS_EV + (64u << 10))
#define WS_FLAG (WS_Q + (64u << 10))
#define WS_VW (32u << 20)  /* VWt2[b][o][h*512+s]: 32..40 MB */
#define WS_INV (40u << 20) /* inv[b][ent][h][e] fp32: 256 KB */

#define CH_TOKS (NB * SL * NH / 4)
#define CH_W (NH * NH / 4)
#define CH_EV (NE * NH / 4)
#define CH_TOTAL (CH_TOKS + 4 * CH_W + CH_EV)

// ---------------------------------------------------------------------------
__global__ void prep_kernel(const float* __restrict__ toks, const float* __restrict__ Wk,
                            const float* __restrict__ Wv, const float* __restrict__ Wo,
                            const float* __restrict__ Wq, const float* __restrict__ ev,
                            const unsigned char* __restrict__ ents,
                            short* __restrict__ toks_bf, short* __restrict__ Wk_bf,
                            short* __restrict__ Wv_bf, short* __restrict__ Wo_bf,
                            short* __restrict__ Wq_bf, short* __restrict__ ev_bf,
                            int* __restrict__ flag) {
    __shared__ int red[256];
    int idx = blockIdx.x * 256 + threadIdx.x;
    if (idx < CH_TOTAL) {
        const float* src;
        short* dst;
        int off = idx;
        if (idx < CH_TOKS) { src = toks; dst = toks_bf; }
        else if (idx < CH_TOKS + CH_W) { src = Wk; dst = Wk_bf; off -= CH_TOKS; }
        else if (idx < CH_TOKS + 2 * CH_W) { src = Wv; dst = Wv_bf; off -= CH_TOKS + CH_W; }
        else if (idx < CH_TOKS + 3 * CH_W) { src = Wo; dst = Wo_bf; off -= CH_TOKS + 2 * CH_W; }
        else if (idx < CH_TOKS + 4 * CH_W) { src = Wq; dst = Wq_bf; off -= CH_TOKS + 3 * CH_W; }
        else { src = ev; dst = ev_bf; off -= CH_TOKS + 4 * CH_W; }
        f32x4 v = ((const f32x4*)src)[off];
        short4v o;
#pragma unroll
        for (int j = 0; j < 4; ++j) o[j] = f2b(v[j]);
        ((short4v*)dst)[off] = o;
    }
    if (blockIdx.x == gridDim.x - 1) {
        int tid = threadIdx.x;
        int cnt = 0;
        for (int j = 0; j < 16; ++j) {
            int off = tid * 16 + j;
            if ((off & 3) != 0 && ents[off] != 0) cnt++;
        }
        red[tid] = cnt;
        __syncthreads();
        for (int s = 128; s > 0; s >>= 1) {
            if (tid < s) red[tid] += red[tid + s];
            __syncthreads();
        }
        if (tid == 0) flag[0] = (red[0] == 0) ? 1 : 0;
    }
}

// ---------------------------------------------------------------------------
// m97 core, 128x128 tile, dbuf + counted vmcnt(8). (proven, R22/R23)
__device__ __forceinline__ void m97_core128(
    const short* __restrict__ Ag, int lda,
    const short* __restrict__ Bg, int ldb, int K,
    short* Alds, short* Blds, int wid, int lane, f32x4 (&acc)[4][4]) {
    int wm = wid >> 1, wn = wid & 1;
    int l15 = lane & 15;
    int rl = lane >> 3;
    int xb = (lane & 7) << 4;
    int kx = (xb ^ (rl << 4)) >> 1;

    const short* aG0 = Ag + (size_t)(wid * 8 + rl) * lda + kx;
    const short* bG0 = Bg + (size_t)(wid * 8 + rl) * ldb + kx;
    size_t aCs = (size_t)32 * lda;
    size_t bCs = (size_t)32 * ldb;

    auto stage = [&](int k0, int buf) {
        short* aL0 = Alds + buf * 8192 + wid * 512;
        short* bL0 = Blds + buf * 8192 + wid * 512;
#pragma unroll
        for (int c = 0; c < 4; ++c) {
            gload16(aG0 + c * aCs + k0, aL0 + c * 2048);
            gload16(bG0 + c * bCs + k0, bL0 + c * 2048);
        }
    };
    auto compute = [&](int buf) {
        const char* Ab = (const char*)(Alds + buf * 8192);
        const char* Bb = (const char*)(Blds + buf * 8192);
#pragma unroll
        for (int kk = 0; kk < 2; ++kk) {
            int x = kk * 64 + ((lane >> 4) << 4);
            short8 af[4], bf_[4];
#pragma unroll
            for (int i = 0; i < 4; ++i) {
                int row = wm * 64 + i * 16 + l15;
                af[i] = *(const short8*)(Ab + row * 128 + (x ^ ((row & 7) << 4)));
            }
#pragma unroll
            for (int j = 0; j < 4; ++j) {
                int row = wn * 64 + j * 16 + l15;
                bf_[j] = *(const short8*)(Bb + row * 128 + (x ^ ((row & 7) << 4)));
            }
            mm44(acc, af, bf_);
        }
    };

    int nsteps = K >> 6;
    stage(0, 0);
    stage(64, 1);
    asm volatile("s_waitcnt vmcnt(8)" ::: "memory");
    __builtin_amdgcn_sched_barrier(0);
    __builtin_amdgcn_s_barrier();

    int buf = 0;
    for (int s = 0; s < nsteps; ++s, buf ^= 1) {
        compute(buf);
        if (s + 1 < nsteps) {
            __builtin_amdgcn_s_barrier();
            if (s + 2 < nsteps) {
                stage((s + 2) * 64, buf);
                asm volatile("s_waitcnt vmcnt(8)" ::: "memory");
            } else {
                asm volatile("s_waitcnt vmcnt(0)" ::: "memory");
            }
            __builtin_amdgcn_sched_barrier(0);
            __builtin_amdgcn_s_barrier();
        }
    }
}

// ---------------------------------------------------------------------------
// m97 core, 64x128 tile, dbuf + counted vmcnt(6). (proven, R23)
__device__ __forceinline__ void m97_core64(
    const short* __restrict__ Ag, int lda,
    const short* __restrict__ Bg, int ldb, int K,
    short* Alds, short* Blds, int wid, int lane, f32x4 (&acc)[4][2]) {
    int l15 = lane & 15;
    int rl = lane >> 3;
    int xb = (lane & 7) << 4;
    int kx = (xb ^ (rl << 4)) >> 1;

    const short* aG0 = Ag + (size_t)(wid * 8 + rl) * lda + kx;
    const short* bG0 = Bg + (size_t)(wid * 8 + rl) * ldb + kx;
    size_t aCs = (size_t)32 * lda;
    size_t bCs = (size_t)32 * ldb;

    auto stage = [&](int k0, int buf) {
        short* aL0 = Alds + buf * 4096 + wid * 512;
        short* bL0 = Blds + buf * 8192 + wid * 512;
        gload16(aG0 + k0, aL0);
        gload16(aG0 + aCs + k0, aL0 + 2048);
#pragma unroll
        for (int c = 0; c < 4; ++c)
            gload16(bG0 + c * bCs + k0, bL0 + c * 2048);
    };
    auto compute = [&](int buf) {
        const char* Ab = (const char*)(Alds + buf * 4096);
        const char* Bb = (const char*)(Blds + buf * 8192);
#pragma unroll
        for (int kk = 0; kk < 2; ++kk) {
            int x = kk * 64 + ((lane >> 4) << 4);
            short8 af[4], bf_[2];
#pragma unroll
            for (int i = 0; i < 4; ++i) {
                int row = i * 16 + l15;
                af[i] = *(const short8*)(Ab + row * 128 + (x ^ ((row & 7) << 4)));
            }
#pragma unroll
            for (int j = 0; j < 2; ++j) {
                int row = wid * 32 + j * 16 + l15;
                bf_[j] = *(const short8*)(Bb + row * 128 + (x ^ ((row & 7) << 4)));
            }
            mm42(acc, af, bf_);
        }
    };

    int nsteps = K >> 6;
    stage(0, 0);
    stage(64, 1);
    asm volatile("s_waitcnt vmcnt(6)" ::: "memory");
    __builtin_amdgcn_sched_barrier(0);
    __builtin_amdgcn_s_barrier();

    int buf = 0;
    for (int s = 0; s < nsteps; ++s, buf ^= 1) {
        compute(buf);
        if (s + 1 < nsteps) {
            __builtin_amdgcn_s_barrier();
            if (s + 2 < nsteps) {
                stage((s + 2) * 64, buf);
                asm volatile("s_waitcnt vmcnt(6)" ::: "memory");
            } else {
                asm volatile("s_waitcnt vmcnt(0)" ::: "memory");
            }
            __builtin_amdgcn_sched_barrier(0);
            __builtin_amdgcn_s_barrier();
        }
    }
}

// ---------------------------------------------------------------------------
// projn: t<256: K/V projection (128x128 tiles); t>=256 (4 blocks): q staged.
__global__ void __launch_bounds__(256, 2)
projn(const short* __restrict__ toks_bf,
      const short* __restrict__ Wk_bf,
      const short* __restrict__ Wv_bf,
      const short* __restrict__ ev_bf,
      const short* __restrict__ Wq_bf,
      const float* __restrict__ bk, const float* __restrict__ bv,
      const float* __restrict__ bq,
      short* __restrict__ K_bf, short* __restrict__ V_bf,
      short* __restrict__ q_bf) {
    __shared__ short Alds[2 * 128 * 64];
    __shared__ short Blds[2 * 128 * 64];
    int t = blockIdx.x;
    int tid = threadIdx.x, lane = tid & 63, wid = tid >> 6;
    int l15 = lane & 15;
    int crow = (lane >> 4) * 4;

    if (t < 256) {
        int l = swz8(t, 32);
        int b = l >> 5, kind = (l >> 4) & 1, mt = (l >> 2) & 3, nt = l & 3;
        const short* Ag = toks_bf + (size_t)(b * SL + mt * 128) * NH;
        const short* Bg = (kind ? Wv_bf : Wk_bf) + (size_t)(nt * 128) * NH;
        const float* bias = kind ? bv : bk;
        short* dst = kind ? V_bf : K_bf;

        f32x4 acc[4][4];
#pragma unroll
        for (int i = 0; i < 4; ++i)
#pragma unroll
            for (int j = 0; j < 4; ++j) acc[i][j] = (f32x4)0.f;

        m97_core128(Ag, NH, Bg, NH, NH, Alds, Blds, wid, lane, acc);

        int wm = wid >> 1, wn = wid & 1;
#pragma unroll
        for (int i = 0; i < 4; ++i)
#pragma unroll
            for (int j = 0; j < 4; ++j) {
                int col = nt * 128 + wn * 64 + j * 16 + l15;
                float bval = bias[col];
                int row0 = b * SL + mt * 128 + wm * 64 + i * 16 + crow;
#pragma unroll
                for (int r = 0; r < 4; ++r)
                    dst[(size_t)(row0 + r) * NH + col] = f2b(acc[i][j][r] + bval);
            }
    } else {
        int tq = t - 256;
        const short* Ag = ev_bf;
        const short* Bg = Wq_bf + (size_t)(tq * 128) * NH;

        f32x4 acc[4][2];
#pragma unroll
        for (int i = 0; i < 4; ++i)
#pragma unroll
            for (int j = 0; j < 2; ++j) acc[i][j] = (f32x4)0.f;

        m97_core64(Ag, NH, Bg, NH, NH, Alds, Blds, wid, lane, acc);

#pragma unroll
        for (int i = 0; i < 4; ++i)
#pragma unroll
            for (int j = 0; j < 2; ++j) {
                int col = tq * 128 + wid * 32 + j * 16 + l15;
                float bval = bq[col];
#pragma unroll
                for (int r = 0; r < 4; ++r) {
                    int row = i * 16 + crow + r;
                    q_bf[(size_t)row * NH + col] = f2b((acc[i][j][r] + bval) * SCALE);
                }
            }
    }
}

// ---------------------------------------------------------------------------
// vwtn_scores: t<256: VWt2 tiles (128x128). t>=256 (64 blocks): scores staged.
__global__ void __launch_bounds__(256, 2)
vwtn_scores(const short* __restrict__ V_bf,
            const short* __restrict__ Wo_bf,
            const short* __restrict__ q_bf,
            const short* __restrict__ K_bf,
            short* __restrict__ VWt,
            short* __restrict__ S_bf) {
    __shared__ short Alds[2 * 128 * 64];
    __shared__ short Blds[2 * 128 * 64];
    int t = blockIdx.x;
    int tid = threadIdx.x, lane = tid & 63, wid = tid >> 6;
    int l15 = lane & 15;
    int crow = (lane >> 4) * 4;

    if (t < 256) {
        int l = swz8(t, 32);
        int bh = l >> 4, mt = (l >> 2) & 3, nt = l & 3;
        int b = bh >> 1, h = bh & 1;

        const short* Ag = Wo_bf + (size_t)(mt * 128) * NH + h * DH;
        const short* Bg = V_bf + (size_t)(b * SL + nt * 128) * NH + h * DH;

        f32x4 acc[4][4];
#pragma unroll
        for (int i = 0; i < 4; ++i)
#pragma unroll
            for (int j = 0; j < 4; ++j) acc[i][j] = (f32x4)0.f;

        m97_core128(Ag, NH, Bg, NH, DH, Alds, Blds, wid, lane, acc);

        int wm = wid >> 1, wn = wid & 1;
        short* dst = VWt + (size_t)b * NH * 1024 + h * 512;
#pragma unroll
        for (int i = 0; i < 4; ++i)
#pragma unroll
            for (int j = 0; j < 4; ++j) {
                int col = nt * 128 + wn * 64 + j * 16 + l15;
                int row0 = mt * 128 + wm * 64 + i * 16 + crow;
#pragma unroll
                for (int r = 0; r < 4; ++r)
                    dst[(size_t)(row0 + r) * 1024 + col] = f2b(acc[i][j][r]);
            }
    } else {
        int l = swz8(t - 256, 8);
        int b = l >> 3, h = (l >> 2) & 1, st = l & 3;

        const short* Ag = q_bf + h * DH;
        const short* Bg = K_bf + (size_t)(b * SL + st * 128) * NH + h * DH;

        f32x4 acc[4][2];
#pragma unroll
        for (int i = 0; i < 4; ++i)
#pragma unroll
            for (int j = 0; j < 2; ++j) acc[i][j] = (f32x4)0.f;

        m97_core64(Ag, NH, Bg, NH, DH, Alds, Blds, wid, lane, acc);

#pragma unroll
        for (int i = 0; i < 4; ++i)
#pragma unroll
            for (int j = 0; j < 2; ++j) {
                int col = st * 128 + wid * 32 + j * 16 + l15;
#pragma unroll
                for (int r = 0; r < 4; ++r) {
                    int row = i * 16 + crow + r;
                    S_bf[(((size_t)(b * HEADS + h)) * NE + row) * SL + col] = f2b(__expf(acc[i][j][r]));
                }
            }
    }
}

// ---------------------------------------------------------------------------
// sums: inv[b][ent][h][e] = 1 / sum_s mask * expS. grid 256. (R12-verified)
__global__ void __launch_bounds__(256, 4)
sums_kernel(const short* __restrict__ S_bf,
            const void* __restrict__ ents,
            const int* __restrict__ flag,
            float* __restrict__ inv) {
    __shared__ unsigned mask_lds[16];
    int l = swz8(blockIdx.x, 32); // b*32 + ent*2 + h
    int b = l >> 5, ent = (l >> 1) & 15, h = l & 1;
    int tid = threadIdx.x;
    if (tid < 16) {
        size_t base = ((size_t)b * EN + ent) * SL + tid * 32;
        unsigned m = 0;
        if (flag[0]) {
            const int* p = (const int*)ents;
            for (int j = 0; j < 32; ++j)
                if (p[base + j]) m |= 1u << j;
        } else {
            const unsigned char* p = (const unsigned char*)ents;
            for (int j = 0; j < 32; ++j)
                if (p[base + j]) m |= 1u << j;
        }
        mask_lds[tid] = m;
    }
    __syncthreads();
    int e = tid >> 2, part = tid & 3;
    const short* sp = S_bf + (((size_t)(b * HEADS + h)) * NE + e) * SL + part * 128;
    float s = 0.f;
#pragma unroll
    for (int c = 0; c < 16; ++c) {
        short8 v = *(const short8*)(sp + c * 8);
        int sidx = part * 128 + c * 8;
        unsigned mb = mask_lds[sidx >> 5] >> (sidx & 31);
#pragma unroll
        for (int j = 0; j < 8; ++j)
            if (mb >> j & 1) s += b2f(v[j]);
    }
    s += __shfl_xor(s, 1);
    s += __shfl_xor(s, 2);
    if (part == 0) inv[(((size_t)b * EN + ent) * HEADS + h) * NE + e] = 1.f / s;
}

// ---------------------------------------------------------------------------
// outgf: out = A @ VWt^T + bo where A[row][k] = mask ? expS*inv : 0 built
// in-kernel (rows = 2 ents x 64 e; k = h*512+s). Staged B (counted vmcnt),
// A built into dbuf swizzled LDS. grid 256 = (b, mt 8, nt 4). 256 thr.
__global__ void __launch_bounds__(256, 2)
outgf(const short* __restrict__ S_bf,
      const short* __restrict__ VWt,
      const void* __restrict__ ents,
      const int* __restrict__ flag,
      const float* __restrict__ inv,
      const float* __restrict__ bo,
      float* __restrict__ out) {
    __shared__ short Ald[2][128 * 64];   // 32 KB
    __shared__ short Bld[2][128 * 64];   // 32 KB
    __shared__ unsigned mask_lds[2][16];
    __shared__ float inv_lds[2][2][64];

    int l = swz8(blockIdx.x, 32); // b*32 + mt*4 + nt
    int b = l >> 5, mt = (l >> 2) & 7, nt = l & 3;
    int tid = threadIdx.x, lane = tid & 63, wid = tid >> 6;
    int l15 = lane & 15, crow = (lane >> 4) * 4;
    int wm = wid >> 1, wn = wid & 1;
    int ent0 = mt * 2;

    // acc must be declared BEFORE the lambdas that capture it.
    f32x4 acc[4][4];
#pragma unroll
    for (int i = 0; i < 4; ++i)
#pragma unroll
        for (int j = 0; j < 4; ++j) acc[i][j] = (f32x4)0.f;

    if (tid < 32) {
        int ei = tid >> 4, w = tid & 15;
        size_t base = ((size_t)b * EN + ent0 + ei) * SL + w * 32;
        unsigned m = 0;
        if (flag[0]) {
            const int* p = (const int*)ents;
            for (int j = 0; j < 32; ++j)
                if (p[base + j]) m |= 1u << j;
        } else {
            const unsigned char* p = (const unsigned char*)ents;
            for (int j = 0; j < 32; ++j)
                if (p[base + j]) m |= 1u << j;
        }
        mask_lds[ei][w] = m;
    }
    {
        int ei = tid >> 7, hh = (tid >> 6) & 1, ee = tid & 63;
        inv_lds[ei][hh][ee] = inv[(((size_t)b * EN + ent0 + ei) * HEADS + hh) * NE + ee];
    }
    __syncthreads();

    // B staging (VWt rows o = nt*128.., cols k = 1024)
    int rl = lane >> 3;
    int kx = (((lane & 7) << 4) ^ (rl << 4)) >> 1;
    const short* bG0 = VWt + ((size_t)b * NH + nt * 128 + wid * 8 + rl) * 1024 + kx;
    size_t bCs = (size_t)32 * 1024;
    auto stageB = [&](int k0, int buf) {
        short* bL0 = &Bld[buf][wid * 512];
#pragma unroll
        for (int c = 0; c < 4; ++c)
            gload16(bG0 + c * bCs + k0, bL0 + c * 2048);
    };

    // A build: thread ae = tid>>2 (e), aseg = (tid&3)*16 (cols of 64)
    int ae = tid >> 2, aseg = (tid & 3) << 4;
    struct BL { short8 r0, r1; };
    auto bload = [&](int kk) -> BL {
        int h = kk >> 9, s0 = kk & 511;
        const short* sp = S_bf + (((size_t)(b * HEADS + h)) * NE + ae) * SL + s0 + aseg;
        BL r;
        r.r0 = *(const short8*)sp;
        r.r1 = *(const short8*)(sp + 8);
        return r;
    };
    auto bwrite = [&](BL bl, int kk, int buf) {
        int h = kk >> 9, s0 = kk & 511;
        int sbit = (s0 + aseg) & 31;
        unsigned mword = (unsigned)(s0 + aseg) >> 5;
#pragma unroll
        for (int ei = 0; ei < 2; ++ei) {
            float iv = inv_lds[ei][h][ae];
            unsigned mbits = mask_lds[ei][mword] >> sbit;
            int row = ei * 64 + ae;
            short8 o0, o1;
#pragma unroll
            for (int j = 0; j < 8; ++j)
                o0[j] = (mbits >> j & 1) ? f2b(b2f(bl.r0[j]) * iv) : (short)0;
#pragma unroll
            for (int j = 0; j < 8; ++j)
                o1[j] = (mbits >> (8 + j) & 1) ? f2b(b2f(bl.r1[j]) * iv) : (short)0;
            short* base = &Ald[buf][row * 64];
            int g0 = aseg >> 3;
            *(short8*)&base[((g0 ^ (row & 7)) << 3)] = o0;
            *(short8*)&base[(((g0 + 1) ^ (row & 7)) << 3)] = o1;
        }
    };

    auto compute = [&](int buf) {
        const char* Ab = (const char*)&Ald[buf][0];
        const char* Bb = (const char*)&Bld[buf][0];
#pragma unroll
        for (int kk = 0; kk < 2; ++kk) {
            int x = kk * 64 + ((lane >> 4) << 4);
            short8 af[4], bf_[4];
#pragma unroll
            for (int i = 0; i < 4; ++i) {
                int row = wm * 64 + i * 16 + l15;
                af[i] = *(const short8*)(Ab + row * 128 + (x ^ ((row & 7) << 4)));
            }
#pragma unroll
            for (int j = 0; j < 4; ++j) {
                int row = wn * 64 + j * 16 + l15;
                bf_[j] = *(const short8*)(Bb + row * 128 + (x ^ ((row & 7) << 4)));
            }
            mm44(acc, af, bf_);
        }
    };

    // prologue: build+stage steps 0 and 1, full drain once.
    {
        BL t0 = bload(0);
        bwrite(t0, 0, 0);
        stageB(0, 0);
        BL t1 = bload(64);
        bwrite(t1, 64, 1);
        stageB(64, 1);
        asm volatile("s_waitcnt vmcnt(0) lgkmcnt(0)" ::: "memory");
        __builtin_amdgcn_sched_barrier(0);
        __builtin_amdgcn_s_barrier();
    }

    int buf = 0;
    BL pend2;
    for (int s = 0; s < 16; ++s, buf ^= 1) {
        if (s + 2 < 16) pend2 = bload((s + 2) * 64); // hidden under compute
        compute(buf);
        if (s < 15) {
            __builtin_amdgcn_s_barrier(); // all reads of buf done
            if (s + 2 < 16) {
                stageB((s + 2) * 64, buf);
                bwrite(pend2, (s + 2) * 64, buf); // compiler waits expS only
                asm volatile("s_waitcnt vmcnt(4) lgkmcnt(0)" ::: "memory");
            } else {
                asm volatile("s_waitcnt vmcnt(0) lgkmcnt(0)" ::: "memory");
            }
            __builtin_amdgcn_sched_barrier(0);
            __builtin_amdgcn_s_barrier();
        }
    }

    // epilogue
    int gr0 = b * 1024 + mt * 128 + wm * 64;
#pragma unroll
    for (int i = 0; i < 4; ++i)
#pragma unroll
        for (int j = 0; j < 4; ++j) {
            int col = nt * 128 + wn * 64 + j * 16 + l15;
            float bval = bo[col];
#pragma unroll
            for (int r = 0; r < 4; ++r) {
                int row = gr0 + i * 16 + crow + r;
                out[(size_t)row * NH + col] = acc[i][j][r] + bval;
            }
        }
}

// ---------------------------------------------------------------------------
extern "C" void kernel_launch(void* const* d_in, const int* in_sizes, int n_in,
                              void* d_out, int out_size, void* d_ws, size_t ws_size,
                              hipStream_t stream) {
    const float* toks = (const float*)d_in[0];
    const void* ents = d_in[1];
    const float* evs = (const float*)d_in[2];
    const float* Wq = (const float*)d_in[6];
    const float* Wk = (const float*)d_in[7];
    const float* Wv = (const float*)d_in[8];
    const float* bq = (const float*)d_in[9];
    const float* bk = (const float*)d_in[10];
    const float* bv = (const float*)d_in[11];
    const float* Wo = (const float*)d_in[12];
    const float* bo = (const float*)d_in[13];

    char* ws = (char*)d_ws;
    short* toks_bf = (short*)(ws + WS_TOKS);
    short* K_bf = (short*)(ws + WS_K);
    short* V_bf = (short*)(ws + WS_V);
    short* S_bf = (short*)(ws + WS_S);
    short* Wk_bf = (short*)(ws + WS_WK);
    short* Wv_bf = (short*)(ws + WS_WV);
    short* Wo_bf = (short*)(ws + WS_WO);
    short* Wq_bf = (short*)(ws + WS_WQ);
    short* ev_bf = (short*)(ws + WS_EV);
    short* q_bf = (short*)(ws + WS_Q);
    int* flag = (int*)(ws + WS_FLAG);
    short* VWt = (short*)(ws + WS_VW);
    float* inv = (float*)(ws + WS_INV);

    prep_kernel<<<CH_TOTAL / 256 + 1, 256, 0, stream>>>(
        toks, Wk, Wv, Wo, Wq, evs, (const unsigned char*)ents,
        toks_bf, Wk_bf, Wv_bf, Wo_bf, Wq_bf, ev_bf, flag);
    projn<<<260, 256, 0, stream>>>(toks_bf, Wk_bf, Wv_bf, ev_bf, Wq_bf,
                                   bk, bv, bq, K_bf, V_bf, q_bf);
    vwtn_scores<<<320, 256, 0, stream>>>(V_bf, Wo_bf, q_bf, K_bf, VWt, S_bf);
    sums_kernel<<<256, 256, 0, stream>>>(S_bf, ents, flag, inv);
    outgf<<<256, 256, 0, stream>>>(S_bf, VWt, ents, flag, inv, bo, (float*)d_out);
}

// Round 26
// 51.455 us; speedup vs baseline: 1.2453x; 1.2453x over previous
//
#include <hip/hip_runtime.h>

// EntityAttention — round 26: exact revert to R23 (proven 51.3 µs best).
// R25's fused A-build regressed 13 µs (redundant per-nt A rebuild + LDS port
// contention + lgkm coupling; P was L2-resident anyway). Pipeline: prep ->
// projn (staged K/V/q) -> vwtn_scores (staged VWt + staged expS scores) ->
// pnorm (P materialization) -> outg (staged dense GEMM).
// NB=8 SL=512 NH=512 EN=16 NE=64 HEADS=2 DH=256.

#define NB 8
#define SL 512
#define NH 512
#define EN 16
#define NE 64
#define HEADS 2
#define DH 256
#define SCALE 0.0625f

typedef __attribute__((ext_vector_type(8))) short short8;
typedef __attribute__((ext_vector_type(4))) short short4v;
typedef __attribute__((ext_vector_type(4))) float f32x4;

#define MFMA16(a, b, c) __builtin_amdgcn_mfma_f32_16x16x32_bf16(a, b, c, 0, 0, 0)

__device__ __forceinline__ short f2b(float f) {
    unsigned u = __builtin_bit_cast(unsigned, f);
    u += 0x7fffu + ((u >> 16) & 1u);
    return (short)(u >> 16);
}
__device__ __forceinline__ float b2f(short s) {
    return __builtin_bit_cast(float, ((unsigned)(unsigned short)s) << 16);
}
__device__ __forceinline__ int swz8(int hw, int chunk) {
    return (hw & 7) * chunk + (hw >> 3);
}

// async global->LDS, 16B per lane; HW writes lane l at ldsbase + l*16.
__device__ __forceinline__ void gload16(const short* g, short* l) {
    __builtin_amdgcn_global_load_lds(
        (const __attribute__((address_space(1))) unsigned int*)g,
        (__attribute__((address_space(3))) unsigned int*)l, 16, 0, 0);
}

__device__ __forceinline__ void mm42(f32x4 (&acc)[4][2], const short8 (&a)[4], const short8 (&bb)[2]) {
#pragma unroll
    for (int i = 0; i < 4; ++i)
#pragma unroll
        for (int j = 0; j < 2; ++j) acc[i][j] = MFMA16(a[i], bb[j], acc[i][j]);
}
__device__ __forceinline__ void mm44(f32x4 (&acc)[4][4], const short8 (&a)[4], const short8 (&bb)[4]) {
#pragma unroll
    for (int i = 0; i < 4; ++i)
#pragma unroll
        for (int j = 0; j < 4; ++j) acc[i][j] = MFMA16(a[i], bb[j], acc[i][j]);
}

// ---- ws byte offsets (aliasing-free layout from R19) -----------------------
#define WS_TOKS 0u
#define WS_K (4u << 20)
#define WS_V (8u << 20)
#define WS_S (20u << 20)
#define WS_WK (22u << 20)
#define WS_WV (WS_WK + (512u << 10))
#define WS_WO (WS_WV + (512u << 10))
#define WS_WQ (WS_WO + (512u << 10))
#define WS_EV (WS_WQ + (512u << 10))
#define WS_Q (WS_EV + (64u << 10))
#define WS_FLAG (WS_Q + (64u << 10))
#define WS_VW (32u << 20)  /* VWt2[b][o][h*512+s]: 32..40 MB */
#define WS_P (40u << 20)   /* P[slot][e][1024]: 40..56.8 MB */

#define CH_TOKS (NB * SL * NH / 4)
#define CH_W (NH * NH / 4)
#define CH_EV (NE * NH / 4)
#define CH_TOTAL (CH_TOKS + 4 * CH_W + CH_EV)

// ---------------------------------------------------------------------------
__global__ void prep_kernel(const float* __restrict__ toks, const float* __restrict__ Wk,
                            const float* __restrict__ Wv, const float* __restrict__ Wo,
                            const float* __restrict__ Wq, const float* __restrict__ ev,
                            const unsigned char* __restrict__ ents,
                            short* __restrict__ toks_bf, short* __restrict__ Wk_bf,
                            short* __restrict__ Wv_bf, short* __restrict__ Wo_bf,
                            short* __restrict__ Wq_bf, short* __restrict__ ev_bf,
                            int* __restrict__ flag) {
    __shared__ int red[256];
    int idx = blockIdx.x * 256 + threadIdx.x;
    if (idx < CH_TOTAL) {
        const float* src;
        short* dst;
        int off = idx;
        if (idx < CH_TOKS) { src = toks; dst = toks_bf; }
        else if (idx < CH_TOKS + CH_W) { src = Wk; dst = Wk_bf; off -= CH_TOKS; }
        else if (idx < CH_TOKS + 2 * CH_W) { src = Wv; dst = Wv_bf; off -= CH_TOKS + CH_W; }
        else if (idx < CH_TOKS + 3 * CH_W) { src = Wo; dst = Wo_bf; off -= CH_TOKS + 2 * CH_W; }
        else if (idx < CH_TOKS + 4 * CH_W) { src = Wq; dst = Wq_bf; off -= CH_TOKS + 3 * CH_W; }
        else { src = ev; dst = ev_bf; off -= CH_TOKS + 4 * CH_W; }
        f32x4 v = ((const f32x4*)src)[off];
        short4v o;
#pragma unroll
        for (int j = 0; j < 4; ++j) o[j] = f2b(v[j]);
        ((short4v*)dst)[off] = o;
    }
    if (blockIdx.x == gridDim.x - 1) {
        int tid = threadIdx.x;
        int cnt = 0;
        for (int j = 0; j < 16; ++j) {
            int off = tid * 16 + j;
            if ((off & 3) != 0 && ents[off] != 0) cnt++;
        }
        red[tid] = cnt;
        __syncthreads();
        for (int s = 128; s > 0; s >>= 1) {
            if (tid < s) red[tid] += red[tid + s];
            __syncthreads();
        }
        if (tid == 0) flag[0] = (red[0] == 0) ? 1 : 0;
    }
}

// ---------------------------------------------------------------------------
// m97 core, 128x128 tile, dbuf + counted vmcnt(8). (proven, R22/R23)
__device__ __forceinline__ void m97_core128(
    const short* __restrict__ Ag, int lda,
    const short* __restrict__ Bg, int ldb, int K,
    short* Alds, short* Blds, int wid, int lane, f32x4 (&acc)[4][4]) {
    int wm = wid >> 1, wn = wid & 1;
    int l15 = lane & 15;
    int rl = lane >> 3;
    int xb = (lane & 7) << 4;
    int kx = (xb ^ (rl << 4)) >> 1;

    const short* aG0 = Ag + (size_t)(wid * 8 + rl) * lda + kx;
    const short* bG0 = Bg + (size_t)(wid * 8 + rl) * ldb + kx;
    size_t aCs = (size_t)32 * lda;
    size_t bCs = (size_t)32 * ldb;

    auto stage = [&](int k0, int buf) {
        short* aL0 = Alds + buf * 8192 + wid * 512;
        short* bL0 = Blds + buf * 8192 + wid * 512;
#pragma unroll
        for (int c = 0; c < 4; ++c) {
            gload16(aG0 + c * aCs + k0, aL0 + c * 2048);
            gload16(bG0 + c * bCs + k0, bL0 + c * 2048);
        }
    };
    auto compute = [&](int buf) {
        const char* Ab = (const char*)(Alds + buf * 8192);
        const char* Bb = (const char*)(Blds + buf * 8192);
#pragma unroll
        for (int kk = 0; kk < 2; ++kk) {
            int x = kk * 64 + ((lane >> 4) << 4);
            short8 af[4], bf_[4];
#pragma unroll
            for (int i = 0; i < 4; ++i) {
                int row = wm * 64 + i * 16 + l15;
                af[i] = *(const short8*)(Ab + row * 128 + (x ^ ((row & 7) << 4)));
            }
#pragma unroll
            for (int j = 0; j < 4; ++j) {
                int row = wn * 64 + j * 16 + l15;
                bf_[j] = *(const short8*)(Bb + row * 128 + (x ^ ((row & 7) << 4)));
            }
            mm44(acc, af, bf_);
        }
    };

    int nsteps = K >> 6;
    stage(0, 0);
    stage(64, 1);
    asm volatile("s_waitcnt vmcnt(8)" ::: "memory");
    __builtin_amdgcn_sched_barrier(0);
    __builtin_amdgcn_s_barrier();

    int buf = 0;
    for (int s = 0; s < nsteps; ++s, buf ^= 1) {
        compute(buf);
        if (s + 1 < nsteps) {
            __builtin_amdgcn_s_barrier();
            if (s + 2 < nsteps) {
                stage((s + 2) * 64, buf);
                asm volatile("s_waitcnt vmcnt(8)" ::: "memory");
            } else {
                asm volatile("s_waitcnt vmcnt(0)" ::: "memory");
            }
            __builtin_amdgcn_sched_barrier(0);
            __builtin_amdgcn_s_barrier();
        }
    }
}

// ---------------------------------------------------------------------------
// m97 core, 64x128 tile, dbuf + counted vmcnt(6). (proven, R23)
__device__ __forceinline__ void m97_core64(
    const short* __restrict__ Ag, int lda,
    const short* __restrict__ Bg, int ldb, int K,
    short* Alds, short* Blds, int wid, int lane, f32x4 (&acc)[4][2]) {
    int l15 = lane & 15;
    int rl = lane >> 3;
    int xb = (lane & 7) << 4;
    int kx = (xb ^ (rl << 4)) >> 1;

    const short* aG0 = Ag + (size_t)(wid * 8 + rl) * lda + kx;
    const short* bG0 = Bg + (size_t)(wid * 8 + rl) * ldb + kx;
    size_t aCs = (size_t)32 * lda;
    size_t bCs = (size_t)32 * ldb;

    auto stage = [&](int k0, int buf) {
        short* aL0 = Alds + buf * 4096 + wid * 512;
        short* bL0 = Blds + buf * 8192 + wid * 512;
        gload16(aG0 + k0, aL0);
        gload16(aG0 + aCs + k0, aL0 + 2048);
#pragma unroll
        for (int c = 0; c < 4; ++c)
            gload16(bG0 + c * bCs + k0, bL0 + c * 2048);
    };
    auto compute = [&](int buf) {
        const char* Ab = (const char*)(Alds + buf * 4096);
        const char* Bb = (const char*)(Blds + buf * 8192);
#pragma unroll
        for (int kk = 0; kk < 2; ++kk) {
            int x = kk * 64 + ((lane >> 4) << 4);
            short8 af[4], bf_[2];
#pragma unroll
            for (int i = 0; i < 4; ++i) {
                int row = i * 16 + l15;
                af[i] = *(const short8*)(Ab + row * 128 + (x ^ ((row & 7) << 4)));
            }
#pragma unroll
            for (int j = 0; j < 2; ++j) {
                int row = wid * 32 + j * 16 + l15;
                bf_[j] = *(const short8*)(Bb + row * 128 + (x ^ ((row & 7) << 4)));
            }
            mm42(acc, af, bf_);
        }
    };

    int nsteps = K >> 6;
    stage(0, 0);
    stage(64, 1);
    asm volatile("s_waitcnt vmcnt(6)" ::: "memory");
    __builtin_amdgcn_sched_barrier(0);
    __builtin_amdgcn_s_barrier();

    int buf = 0;
    for (int s = 0; s < nsteps; ++s, buf ^= 1) {
        compute(buf);
        if (s + 1 < nsteps) {
            __builtin_amdgcn_s_barrier();
            if (s + 2 < nsteps) {
                stage((s + 2) * 64, buf);
                asm volatile("s_waitcnt vmcnt(6)" ::: "memory");
            } else {
                asm volatile("s_waitcnt vmcnt(0)" ::: "memory");
            }
            __builtin_amdgcn_sched_barrier(0);
            __builtin_amdgcn_s_barrier();
        }
    }
}

// ---------------------------------------------------------------------------
// projn: t<256: K/V projection (128x128 tiles); t>=256 (4 blocks): q staged.
__global__ void __launch_bounds__(256, 2)
projn(const short* __restrict__ toks_bf,
      const short* __restrict__ Wk_bf,
      const short* __restrict__ Wv_bf,
      const short* __restrict__ ev_bf,
      const short* __restrict__ Wq_bf,
      const float* __restrict__ bk, const float* __restrict__ bv,
      const float* __restrict__ bq,
      short* __restrict__ K_bf, short* __restrict__ V_bf,
      short* __restrict__ q_bf) {
    __shared__ short Alds[2 * 128 * 64];
    __shared__ short Blds[2 * 128 * 64];
    int t = blockIdx.x;
    int tid = threadIdx.x, lane = tid & 63, wid = tid >> 6;
    int l15 = lane & 15;
    int crow = (lane >> 4) * 4;

    if (t < 256) {
        int l = swz8(t, 32);
        int b = l >> 5, kind = (l >> 4) & 1, mt = (l >> 2) & 3, nt = l & 3;
        const short* Ag = toks_bf + (size_t)(b * SL + mt * 128) * NH;
        const short* Bg = (kind ? Wv_bf : Wk_bf) + (size_t)(nt * 128) * NH;
        const float* bias = kind ? bv : bk;
        short* dst = kind ? V_bf : K_bf;

        f32x4 acc[4][4];
#pragma unroll
        for (int i = 0; i < 4; ++i)
#pragma unroll
            for (int j = 0; j < 4; ++j) acc[i][j] = (f32x4)0.f;

        m97_core128(Ag, NH, Bg, NH, NH, Alds, Blds, wid, lane, acc);

        int wm = wid >> 1, wn = wid & 1;
#pragma unroll
        for (int i = 0; i < 4; ++i)
#pragma unroll
            for (int j = 0; j < 4; ++j) {
                int col = nt * 128 + wn * 64 + j * 16 + l15;
                float bval = bias[col];
                int row0 = b * SL + mt * 128 + wm * 64 + i * 16 + crow;
#pragma unroll
                for (int r = 0; r < 4; ++r)
                    dst[(size_t)(row0 + r) * NH + col] = f2b(acc[i][j][r] + bval);
            }
    } else {
        // q staged: M=64 events, N = 128 cols per block (4 blocks), K=512.
        int tq = t - 256;
        const short* Ag = ev_bf;
        const short* Bg = Wq_bf + (size_t)(tq * 128) * NH;

        f32x4 acc[4][2];
#pragma unroll
        for (int i = 0; i < 4; ++i)
#pragma unroll
            for (int j = 0; j < 2; ++j) acc[i][j] = (f32x4)0.f;

        m97_core64(Ag, NH, Bg, NH, NH, Alds, Blds, wid, lane, acc);

#pragma unroll
        for (int i = 0; i < 4; ++i)
#pragma unroll
            for (int j = 0; j < 2; ++j) {
                int col = tq * 128 + wid * 32 + j * 16 + l15;
                float bval = bq[col];
#pragma unroll
                for (int r = 0; r < 4; ++r) {
                    int row = i * 16 + crow + r;
                    q_bf[(size_t)row * NH + col] = f2b((acc[i][j][r] + bval) * SCALE);
                }
            }
    }
}

// ---------------------------------------------------------------------------
// vwtn_scores: t<256: VWt2 tiles (128x128). t>=256 (64 blocks): scores staged
// (64x128 tiles, K=DH=256), epilogue applies expf.
__global__ void __launch_bounds__(256, 2)
vwtn_scores(const short* __restrict__ V_bf,
            const short* __restrict__ Wo_bf,
            const short* __restrict__ q_bf,
            const short* __restrict__ K_bf,
            short* __restrict__ VWt,
            short* __restrict__ S_bf) {
    __shared__ short Alds[2 * 128 * 64];
    __shared__ short Blds[2 * 128 * 64];
    int t = blockIdx.x;
    int tid = threadIdx.x, lane = tid & 63, wid = tid >> 6;
    int l15 = lane & 15;
    int crow = (lane >> 4) * 4;

    if (t < 256) {
        int l = swz8(t, 32);
        int bh = l >> 4, mt = (l >> 2) & 3, nt = l & 3;
        int b = bh >> 1, h = bh & 1;

        const short* Ag = Wo_bf + (size_t)(mt * 128) * NH + h * DH;
        const short* Bg = V_bf + (size_t)(b * SL + nt * 128) * NH + h * DH;

        f32x4 acc[4][4];
#pragma unroll
        for (int i = 0; i < 4; ++i)
#pragma unroll
            for (int j = 0; j < 4; ++j) acc[i][j] = (f32x4)0.f;

        m97_core128(Ag, NH, Bg, NH, DH, Alds, Blds, wid, lane, acc);

        int wm = wid >> 1, wn = wid & 1;
        short* dst = VWt + (size_t)b * NH * 1024 + h * 512;
#pragma unroll
        for (int i = 0; i < 4; ++i)
#pragma unroll
            for (int j = 0; j < 4; ++j) {
                int col = nt * 128 + wn * 64 + j * 16 + l15;     // s
                int row0 = mt * 128 + wm * 64 + i * 16 + crow;   // o
#pragma unroll
                for (int r = 0; r < 4; ++r)
                    dst[(size_t)(row0 + r) * 1024 + col] = f2b(acc[i][j][r]);
            }
    } else {
        // scores staged: S_bf[b][h][e][s] = EXP(q . K). 64 blocks, 64x128.
        int l = swz8(t - 256, 8);
        int b = l >> 3, h = (l >> 2) & 1, st = l & 3;

        const short* Ag = q_bf + h * DH;
        const short* Bg = K_bf + (size_t)(b * SL + st * 128) * NH + h * DH;

        f32x4 acc[4][2];
#pragma unroll
        for (int i = 0; i < 4; ++i)
#pragma unroll
            for (int j = 0; j < 2; ++j) acc[i][j] = (f32x4)0.f;

        m97_core64(Ag, NH, Bg, NH, DH, Alds, Blds, wid, lane, acc);

#pragma unroll
        for (int i = 0; i < 4; ++i)
#pragma unroll
            for (int j = 0; j < 2; ++j) {
                int col = st * 128 + wid * 32 + j * 16 + l15;
#pragma unroll
                for (int r = 0; r < 4; ++r) {
                    int row = i * 16 + crow + r;
                    S_bf[(((size_t)(b * HEADS + h)) * NE + row) * SL + col] = f2b(__expf(acc[i][j][r]));
                }
            }
    }
}

// ---------------------------------------------------------------------------
// pnorm: P[(b*16+ent)*64+e][h*512+s] = mask ? expS*inv : 0. grid 256.
__global__ void __launch_bounds__(256, 4)
pnorm_kernel(const short* __restrict__ S_bf,
             const void* __restrict__ ents,
             const int* __restrict__ flag,
             short* __restrict__ P) {
    int l = swz8(blockIdx.x, 32); // b*32 + ent*2 + eh
    int b = l >> 5, ent = (l >> 1) & 15, eh = l & 1;
    int tid = threadIdx.x, lane = tid & 63, wid = tid >> 6;

    unsigned att8 = 0;
    {
        size_t mbase = ((size_t)b * EN + ent) * SL + lane * 8;
        if (flag[0]) {
            const int* p = (const int*)ents;
#pragma unroll
            for (int j = 0; j < 8; ++j)
                if (p[mbase + j]) att8 |= 1u << j;
        } else {
            const unsigned char* p = (const unsigned char*)ents;
#pragma unroll
            for (int j = 0; j < 8; ++j)
                if (p[mbase + j]) att8 |= 1u << j;
        }
    }

    for (int it = 0; it < 8; ++it) {
        int e = eh * 32 + wid * 8 + it;
        const short* s0p = S_bf + (((size_t)(b * HEADS + 0)) * NE + e) * SL + lane * 8;
        const short* s1p = S_bf + (((size_t)(b * HEADS + 1)) * NE + e) * SL + lane * 8;
        short8 v0 = *(const short8*)s0p;
        short8 v1 = *(const short8*)s1p;
        float f0[8], f1[8], sum0 = 0.f, sum1 = 0.f;
#pragma unroll
        for (int j = 0; j < 8; ++j) {
            f0[j] = (att8 >> j & 1) ? b2f(v0[j]) : 0.f;
            f1[j] = (att8 >> j & 1) ? b2f(v1[j]) : 0.f;
            sum0 += f0[j];
            sum1 += f1[j];
        }
#pragma unroll
        for (int off = 32; off; off >>= 1) {
            sum0 += __shfl_xor(sum0, off);
            sum1 += __shfl_xor(sum1, off);
        }
        float iv0 = 1.f / sum0, iv1 = 1.f / sum1;
        short8 o0, o1;
#pragma unroll
        for (int j = 0; j < 8; ++j) {
            o0[j] = f2b(f0[j] * iv0);
            o1[j] = f2b(f1[j] * iv1);
        }
        short* prow = P + ((size_t)(b * EN + ent) * NE + e) * 1024;
        *(short8*)(prow + lane * 8) = o0;
        *(short8*)(prow + 512 + lane * 8) = o1;
    }
}

// ---------------------------------------------------------------------------
// outg: out = P @ VWt2^T + bo. M=8192, N=512, K=1024. 128x128 tiles, grid 256.
__global__ void __launch_bounds__(256, 2)
outg(const short* __restrict__ P,
     const short* __restrict__ VWt,
     const float* __restrict__ bo,
     float* __restrict__ out) {
    __shared__ short Alds[2 * 128 * 64];
    __shared__ short Blds[2 * 128 * 64];
    int l = swz8(blockIdx.x, 32); // b*32 + mt*4 + nt
    int b = l >> 5, mt = (l >> 2) & 7, nt = l & 3;
    int tid = threadIdx.x, lane = tid & 63, wid = tid >> 6;
    int l15 = lane & 15;
    int crow = (lane >> 4) * 4;

    const short* Ag = P + ((size_t)b * 1024 + mt * 128) * 1024;
    const short* Bg = VWt + ((size_t)b * NH + nt * 128) * 1024;

    f32x4 acc[4][4];
#pragma unroll
    for (int i = 0; i < 4; ++i)
#pragma unroll
        for (int j = 0; j < 4; ++j) acc[i][j] = (f32x4)0.f;

    m97_core128(Ag, 1024, Bg, 1024, 1024, Alds, Blds, wid, lane, acc);

    int wm = wid >> 1, wn = wid & 1;
    int gr0 = b * 1024 + mt * 128 + wm * 64;
#pragma unroll
    for (int i = 0; i < 4; ++i)
#pragma unroll
        for (int j = 0; j < 4; ++j) {
            int col = nt * 128 + wn * 64 + j * 16 + l15;
            float bval = bo[col];
#pragma unroll
            for (int r = 0; r < 4; ++r) {
                int row = gr0 + i * 16 + crow + r;
                out[(size_t)row * NH + col] = acc[i][j][r] + bval;
            }
        }
}

// ---------------------------------------------------------------------------
extern "C" void kernel_launch(void* const* d_in, const int* in_sizes, int n_in,
                              void* d_out, int out_size, void* d_ws, size_t ws_size,
                              hipStream_t stream) {
    const float* toks = (const float*)d_in[0];
    const void* ents = d_in[1];
    const float* evs = (const float*)d_in[2];
    const float* Wq = (const float*)d_in[6];
    const float* Wk = (const float*)d_in[7];
    const float* Wv = (const float*)d_in[8];
    const float* bq = (const float*)d_in[9];
    const float* bk = (const float*)d_in[10];
    const float* bv = (const float*)d_in[11];
    const float* Wo = (const float*)d_in[12];
    const float* bo = (const float*)d_in[13];

    char* ws = (char*)d_ws;
    short* toks_bf = (short*)(ws + WS_TOKS);
    short* K_bf = (short*)(ws + WS_K);
    short* V_bf = (short*)(ws + WS_V);
    short* S_bf = (short*)(ws + WS_S);
    short* Wk_bf = (short*)(ws + WS_WK);
    short* Wv_bf = (short*)(ws + WS_WV);
    short* Wo_bf = (short*)(ws + WS_WO);
    short* Wq_bf = (short*)(ws + WS_WQ);
    short* ev_bf = (short*)(ws + WS_EV);
    short* q_bf = (short*)(ws + WS_Q);
    int* flag = (int*)(ws + WS_FLAG);
    short* VWt = (short*)(ws + WS_VW);
    short* P = (short*)(ws + WS_P);

    prep_kernel<<<CH_TOTAL / 256 + 1, 256, 0, stream>>>(
        toks, Wk, Wv, Wo, Wq, evs, (const unsigned char*)ents,
        toks_bf, Wk_bf, Wv_bf, Wo_bf, Wq_bf, ev_bf, flag);
    projn<<<260, 256, 0, stream>>>(toks_bf, Wk_bf, Wv_bf, ev_bf, Wq_bf,
                                   bk, bv, bq, K_bf, V_bf, q_bf);
    vwtn_scores<<<320, 256, 0, stream>>>(V_bf, Wo_bf, q_bf, K_bf, VWt, S_bf);
    pnorm_kernel<<<256, 256, 0, stream>>>(S_bf, ents, flag, P);
    outg<<<256, 256, 0, stream>>>(P, VWt, bo, (float*)d_out);
}

// Round 27
// 50.624 us; speedup vs baseline: 1.2657x; 1.0164x over previous
//
#include <hip/hip_runtime.h>

// EntityAttention — round 27: R26 base (51.4 µs) with outg split to 128x64
// tiles / 512 blocks so the final GEMM gets 2 blocks/CU co-residency (it was
// the only launch at exactly 1 block/CU). Core = R19 128x64 geometry +
// R22 counted-vmcnt(6) schedule. Everything else identical to R26.
// NB=8 SL=512 NH=512 EN=16 NE=64 HEADS=2 DH=256.

#define NB 8
#define SL 512
#define NH 512
#define EN 16
#define NE 64
#define HEADS 2
#define DH 256
#define SCALE 0.0625f

typedef __attribute__((ext_vector_type(8))) short short8;
typedef __attribute__((ext_vector_type(4))) short short4v;
typedef __attribute__((ext_vector_type(4))) float f32x4;

#define MFMA16(a, b, c) __builtin_amdgcn_mfma_f32_16x16x32_bf16(a, b, c, 0, 0, 0)

__device__ __forceinline__ short f2b(float f) {
    unsigned u = __builtin_bit_cast(unsigned, f);
    u += 0x7fffu + ((u >> 16) & 1u);
    return (short)(u >> 16);
}
__device__ __forceinline__ float b2f(short s) {
    return __builtin_bit_cast(float, ((unsigned)(unsigned short)s) << 16);
}
__device__ __forceinline__ int swz8(int hw, int chunk) {
    return (hw & 7) * chunk + (hw >> 3);
}

// async global->LDS, 16B per lane; HW writes lane l at ldsbase + l*16.
__device__ __forceinline__ void gload16(const short* g, short* l) {
    __builtin_amdgcn_global_load_lds(
        (const __attribute__((address_space(1))) unsigned int*)g,
        (__attribute__((address_space(3))) unsigned int*)l, 16, 0, 0);
}

__device__ __forceinline__ void mm42(f32x4 (&acc)[4][2], const short8 (&a)[4], const short8 (&bb)[2]) {
#pragma unroll
    for (int i = 0; i < 4; ++i)
#pragma unroll
        for (int j = 0; j < 2; ++j) acc[i][j] = MFMA16(a[i], bb[j], acc[i][j]);
}
__device__ __forceinline__ void mm44(f32x4 (&acc)[4][4], const short8 (&a)[4], const short8 (&bb)[4]) {
#pragma unroll
    for (int i = 0; i < 4; ++i)
#pragma unroll
        for (int j = 0; j < 4; ++j) acc[i][j] = MFMA16(a[i], bb[j], acc[i][j]);
}

// ---- ws byte offsets (aliasing-free layout from R19) -----------------------
#define WS_TOKS 0u
#define WS_K (4u << 20)
#define WS_V (8u << 20)
#define WS_S (20u << 20)
#define WS_WK (22u << 20)
#define WS_WV (WS_WK + (512u << 10))
#define WS_WO (WS_WV + (512u << 10))
#define WS_WQ (WS_WO + (512u << 10))
#define WS_EV (WS_WQ + (512u << 10))
#define WS_Q (WS_EV + (64u << 10))
#define WS_FLAG (WS_Q + (64u << 10))
#define WS_VW (32u << 20)  /* VWt2[b][o][h*512+s]: 32..40 MB */
#define WS_P (40u << 20)   /* P[slot][e][1024]: 40..56.8 MB */

#define CH_TOKS (NB * SL * NH / 4)
#define CH_W (NH * NH / 4)
#define CH_EV (NE * NH / 4)
#define CH_TOTAL (CH_TOKS + 4 * CH_W + CH_EV)

// ---------------------------------------------------------------------------
__global__ void prep_kernel(const float* __restrict__ toks, const float* __restrict__ Wk,
                            const float* __restrict__ Wv, const float* __restrict__ Wo,
                            const float* __restrict__ Wq, const float* __restrict__ ev,
                            const unsigned char* __restrict__ ents,
                            short* __restrict__ toks_bf, short* __restrict__ Wk_bf,
                            short* __restrict__ Wv_bf, short* __restrict__ Wo_bf,
                            short* __restrict__ Wq_bf, short* __restrict__ ev_bf,
                            int* __restrict__ flag) {
    __shared__ int red[256];
    int idx = blockIdx.x * 256 + threadIdx.x;
    if (idx < CH_TOTAL) {
        const float* src;
        short* dst;
        int off = idx;
        if (idx < CH_TOKS) { src = toks; dst = toks_bf; }
        else if (idx < CH_TOKS + CH_W) { src = Wk; dst = Wk_bf; off -= CH_TOKS; }
        else if (idx < CH_TOKS + 2 * CH_W) { src = Wv; dst = Wv_bf; off -= CH_TOKS + CH_W; }
        else if (idx < CH_TOKS + 3 * CH_W) { src = Wo; dst = Wo_bf; off -= CH_TOKS + 2 * CH_W; }
        else if (idx < CH_TOKS + 4 * CH_W) { src = Wq; dst = Wq_bf; off -= CH_TOKS + 3 * CH_W; }
        else { src = ev; dst = ev_bf; off -= CH_TOKS + 4 * CH_W; }
        f32x4 v = ((const f32x4*)src)[off];
        short4v o;
#pragma unroll
        for (int j = 0; j < 4; ++j) o[j] = f2b(v[j]);
        ((short4v*)dst)[off] = o;
    }
    if (blockIdx.x == gridDim.x - 1) {
        int tid = threadIdx.x;
        int cnt = 0;
        for (int j = 0; j < 16; ++j) {
            int off = tid * 16 + j;
            if ((off & 3) != 0 && ents[off] != 0) cnt++;
        }
        red[tid] = cnt;
        __syncthreads();
        for (int s = 128; s > 0; s >>= 1) {
            if (tid < s) red[tid] += red[tid + s];
            __syncthreads();
        }
        if (tid == 0) flag[0] = (red[0] == 0) ? 1 : 0;
    }
}

// ---------------------------------------------------------------------------
// m97 core, 128x128 tile, dbuf + counted vmcnt(8). (proven, R22/R23)
__device__ __forceinline__ void m97_core128(
    const short* __restrict__ Ag, int lda,
    const short* __restrict__ Bg, int ldb, int K,
    short* Alds, short* Blds, int wid, int lane, f32x4 (&acc)[4][4]) {
    int wm = wid >> 1, wn = wid & 1;
    int l15 = lane & 15;
    int rl = lane >> 3;
    int xb = (lane & 7) << 4;
    int kx = (xb ^ (rl << 4)) >> 1;

    const short* aG0 = Ag + (size_t)(wid * 8 + rl) * lda + kx;
    const short* bG0 = Bg + (size_t)(wid * 8 + rl) * ldb + kx;
    size_t aCs = (size_t)32 * lda;
    size_t bCs = (size_t)32 * ldb;

    auto stage = [&](int k0, int buf) {
        short* aL0 = Alds + buf * 8192 + wid * 512;
        short* bL0 = Blds + buf * 8192 + wid * 512;
#pragma unroll
        for (int c = 0; c < 4; ++c) {
            gload16(aG0 + c * aCs + k0, aL0 + c * 2048);
            gload16(bG0 + c * bCs + k0, bL0 + c * 2048);
        }
    };
    auto compute = [&](int buf) {
        const char* Ab = (const char*)(Alds + buf * 8192);
        const char* Bb = (const char*)(Blds + buf * 8192);
#pragma unroll
        for (int kk = 0; kk < 2; ++kk) {
            int x = kk * 64 + ((lane >> 4) << 4);
            short8 af[4], bf_[4];
#pragma unroll
            for (int i = 0; i < 4; ++i) {
                int row = wm * 64 + i * 16 + l15;
                af[i] = *(const short8*)(Ab + row * 128 + (x ^ ((row & 7) << 4)));
            }
#pragma unroll
            for (int j = 0; j < 4; ++j) {
                int row = wn * 64 + j * 16 + l15;
                bf_[j] = *(const short8*)(Bb + row * 128 + (x ^ ((row & 7) << 4)));
            }
            mm44(acc, af, bf_);
        }
    };

    int nsteps = K >> 6;
    stage(0, 0);
    stage(64, 1);
    asm volatile("s_waitcnt vmcnt(8)" ::: "memory");
    __builtin_amdgcn_sched_barrier(0);
    __builtin_amdgcn_s_barrier();

    int buf = 0;
    for (int s = 0; s < nsteps; ++s, buf ^= 1) {
        compute(buf);
        if (s + 1 < nsteps) {
            __builtin_amdgcn_s_barrier();
            if (s + 2 < nsteps) {
                stage((s + 2) * 64, buf);
                asm volatile("s_waitcnt vmcnt(8)" ::: "memory");
            } else {
                asm volatile("s_waitcnt vmcnt(0)" ::: "memory");
            }
            __builtin_amdgcn_sched_barrier(0);
            __builtin_amdgcn_s_barrier();
        }
    }
}

// ---------------------------------------------------------------------------
// m97 core, 64x128 tile (A=64 rows shared -> output rows; B=128 rows ->
// output cols, wave owns 32), dbuf + counted vmcnt(6). (proven, R23)
__device__ __forceinline__ void m97_core64(
    const short* __restrict__ Ag, int lda,
    const short* __restrict__ Bg, int ldb, int K,
    short* Alds, short* Blds, int wid, int lane, f32x4 (&acc)[4][2]) {
    int l15 = lane & 15;
    int rl = lane >> 3;
    int xb = (lane & 7) << 4;
    int kx = (xb ^ (rl << 4)) >> 1;

    const short* aG0 = Ag + (size_t)(wid * 8 + rl) * lda + kx;
    const short* bG0 = Bg + (size_t)(wid * 8 + rl) * ldb + kx;
    size_t aCs = (size_t)32 * lda;
    size_t bCs = (size_t)32 * ldb;

    auto stage = [&](int k0, int buf) {
        short* aL0 = Alds + buf * 4096 + wid * 512;
        short* bL0 = Blds + buf * 8192 + wid * 512;
        gload16(aG0 + k0, aL0);
        gload16(aG0 + aCs + k0, aL0 + 2048);
#pragma unroll
        for (int c = 0; c < 4; ++c)
            gload16(bG0 + c * bCs + k0, bL0 + c * 2048);
    };
    auto compute = [&](int buf) {
        const char* Ab = (const char*)(Alds + buf * 4096);
        const char* Bb = (const char*)(Blds + buf * 8192);
#pragma unroll
        for (int kk = 0; kk < 2; ++kk) {
            int x = kk * 64 + ((lane >> 4) << 4);
            short8 af[4], bf_[2];
#pragma unroll
            for (int i = 0; i < 4; ++i) {
                int row = i * 16 + l15;
                af[i] = *(const short8*)(Ab + row * 128 + (x ^ ((row & 7) << 4)));
            }
#pragma unroll
            for (int j = 0; j < 2; ++j) {
                int row = wid * 32 + j * 16 + l15;
                bf_[j] = *(const short8*)(Bb + row * 128 + (x ^ ((row & 7) << 4)));
            }
            mm42(acc, af, bf_);
        }
    };

    int nsteps = K >> 6;
    stage(0, 0);
    stage(64, 1);
    asm volatile("s_waitcnt vmcnt(6)" ::: "memory");
    __builtin_amdgcn_sched_barrier(0);
    __builtin_amdgcn_s_barrier();

    int buf = 0;
    for (int s = 0; s < nsteps; ++s, buf ^= 1) {
        compute(buf);
        if (s + 1 < nsteps) {
            __builtin_amdgcn_s_barrier();
            if (s + 2 < nsteps) {
                stage((s + 2) * 64, buf);
                asm volatile("s_waitcnt vmcnt(6)" ::: "memory");
            } else {
                asm volatile("s_waitcnt vmcnt(0)" ::: "memory");
            }
            __builtin_amdgcn_sched_barrier(0);
            __builtin_amdgcn_s_barrier();
        }
    }
}

// ---------------------------------------------------------------------------
// m97 core, 128x64 tile (A=128 rows -> output rows, wave pair owns 64;
// B=64 rows -> output cols, wave owns 32), dbuf + counted vmcnt(6).
// Geometry = R16-R19 proven core; schedule = R22 counted vmcnt.
__device__ __forceinline__ void m97_core128x64(
    const short* __restrict__ Ag, int lda,
    const short* __restrict__ Bg, int ldb, int K,
    short* Alds, short* Blds, int wid, int lane, f32x4 (&acc)[4][2]) {
    int wm = wid >> 1, wn = wid & 1;
    int l15 = lane & 15;
    int rl = lane >> 3;
    int xb = (lane & 7) << 4;
    int kx = (xb ^ (rl << 4)) >> 1;

    const short* aG0 = Ag + (size_t)(wid * 8 + rl) * lda + kx;
    const short* bG0 = Bg + (size_t)(wid * 8 + rl) * ldb + kx;
    size_t aCs = (size_t)32 * lda;
    size_t bCs = (size_t)32 * ldb;

    auto stage = [&](int k0, int buf) {
        short* aL0 = Alds + buf * 8192 + wid * 512; // A: 128 rows (4 chunks)
        short* bL0 = Blds + buf * 4096 + wid * 512; // B: 64 rows (2 chunks)
#pragma unroll
        for (int c = 0; c < 4; ++c)
            gload16(aG0 + c * aCs + k0, aL0 + c * 2048);
        gload16(bG0 + k0, bL0);
        gload16(bG0 + bCs + k0, bL0 + 2048);
    };
    auto compute = [&](int buf) {
        const char* Ab = (const char*)(Alds + buf * 8192);
        const char* Bb = (const char*)(Blds + buf * 4096);
#pragma unroll
        for (int kk = 0; kk < 2; ++kk) {
            int x = kk * 64 + ((lane >> 4) << 4);
            short8 af[4], bf_[2];
#pragma unroll
            for (int i = 0; i < 4; ++i) {
                int row = wm * 64 + i * 16 + l15;
                af[i] = *(const short8*)(Ab + row * 128 + (x ^ ((row & 7) << 4)));
            }
#pragma unroll
            for (int j = 0; j < 2; ++j) {
                int row = wn * 32 + j * 16 + l15;
                bf_[j] = *(const short8*)(Bb + row * 128 + (x ^ ((row & 7) << 4)));
            }
            mm42(acc, af, bf_);
        }
    };

    int nsteps = K >> 6;
    stage(0, 0);
    stage(64, 1);
    asm volatile("s_waitcnt vmcnt(6)" ::: "memory");
    __builtin_amdgcn_sched_barrier(0);
    __builtin_amdgcn_s_barrier();

    int buf = 0;
    for (int s = 0; s < nsteps; ++s, buf ^= 1) {
        compute(buf);
        if (s + 1 < nsteps) {
            __builtin_amdgcn_s_barrier();
            if (s + 2 < nsteps) {
                stage((s + 2) * 64, buf);
                asm volatile("s_waitcnt vmcnt(6)" ::: "memory");
            } else {
                asm volatile("s_waitcnt vmcnt(0)" ::: "memory");
            }
            __builtin_amdgcn_sched_barrier(0);
            __builtin_amdgcn_s_barrier();
        }
    }
}

// ---------------------------------------------------------------------------
// projn: t<256: K/V projection (128x128 tiles); t>=256 (4 blocks): q staged.
__global__ void __launch_bounds__(256, 2)
projn(const short* __restrict__ toks_bf,
      const short* __restrict__ Wk_bf,
      const short* __restrict__ Wv_bf,
      const short* __restrict__ ev_bf,
      const short* __restrict__ Wq_bf,
      const float* __restrict__ bk, const float* __restrict__ bv,
      const float* __restrict__ bq,
      short* __restrict__ K_bf, short* __restrict__ V_bf,
      short* __restrict__ q_bf) {
    __shared__ short Alds[2 * 128 * 64];
    __shared__ short Blds[2 * 128 * 64];
    int t = blockIdx.x;
    int tid = threadIdx.x, lane = tid & 63, wid = tid >> 6;
    int l15 = lane & 15;
    int crow = (lane >> 4) * 4;

    if (t < 256) {
        int l = swz8(t, 32);
        int b = l >> 5, kind = (l >> 4) & 1, mt = (l >> 2) & 3, nt = l & 3;
        const short* Ag = toks_bf + (size_t)(b * SL + mt * 128) * NH;
        const short* Bg = (kind ? Wv_bf : Wk_bf) + (size_t)(nt * 128) * NH;
        const float* bias = kind ? bv : bk;
        short* dst = kind ? V_bf : K_bf;

        f32x4 acc[4][4];
#pragma unroll
        for (int i = 0; i < 4; ++i)
#pragma unroll
            for (int j = 0; j < 4; ++j) acc[i][j] = (f32x4)0.f;

        m97_core128(Ag, NH, Bg, NH, NH, Alds, Blds, wid, lane, acc);

        int wm = wid >> 1, wn = wid & 1;
#pragma unroll
        for (int i = 0; i < 4; ++i)
#pragma unroll
            for (int j = 0; j < 4; ++j) {
                int col = nt * 128 + wn * 64 + j * 16 + l15;
                float bval = bias[col];
                int row0 = b * SL + mt * 128 + wm * 64 + i * 16 + crow;
#pragma unroll
                for (int r = 0; r < 4; ++r)
                    dst[(size_t)(row0 + r) * NH + col] = f2b(acc[i][j][r] + bval);
            }
    } else {
        // q staged: M=64 events, N = 128 cols per block (4 blocks), K=512.
        int tq = t - 256;
        const short* Ag = ev_bf;
        const short* Bg = Wq_bf + (size_t)(tq * 128) * NH;

        f32x4 acc[4][2];
#pragma unroll
        for (int i = 0; i < 4; ++i)
#pragma unroll
            for (int j = 0; j < 2; ++j) acc[i][j] = (f32x4)0.f;

        m97_core64(Ag, NH, Bg, NH, NH, Alds, Blds, wid, lane, acc);

#pragma unroll
        for (int i = 0; i < 4; ++i)
#pragma unroll
            for (int j = 0; j < 2; ++j) {
                int col = tq * 128 + wid * 32 + j * 16 + l15;
                float bval = bq[col];
#pragma unroll
                for (int r = 0; r < 4; ++r) {
                    int row = i * 16 + crow + r;
                    q_bf[(size_t)row * NH + col] = f2b((acc[i][j][r] + bval) * SCALE);
                }
            }
    }
}

// ---------------------------------------------------------------------------
// vwtn_scores: t<256: VWt2 tiles (128x128). t>=256 (64 blocks): scores staged
// (64x128 tiles, K=DH=256), epilogue applies expf.
__global__ void __launch_bounds__(256, 2)
vwtn_scores(const short* __restrict__ V_bf,
            const short* __restrict__ Wo_bf,
            const short* __restrict__ q_bf,
            const short* __restrict__ K_bf,
            short* __restrict__ VWt,
            short* __restrict__ S_bf) {
    __shared__ short Alds[2 * 128 * 64];
    __shared__ short Blds[2 * 128 * 64];
    int t = blockIdx.x;
    int tid = threadIdx.x, lane = tid & 63, wid = tid >> 6;
    int l15 = lane & 15;
    int crow = (lane >> 4) * 4;

    if (t < 256) {
        int l = swz8(t, 32);
        int bh = l >> 4, mt = (l >> 2) & 3, nt = l & 3;
        int b = bh >> 1, h = bh & 1;

        const short* Ag = Wo_bf + (size_t)(mt * 128) * NH + h * DH;
        const short* Bg = V_bf + (size_t)(b * SL + nt * 128) * NH + h * DH;

        f32x4 acc[4][4];
#pragma unroll
        for (int i = 0; i < 4; ++i)
#pragma unroll
            for (int j = 0; j < 4; ++j) acc[i][j] = (f32x4)0.f;

        m97_core128(Ag, NH, Bg, NH, DH, Alds, Blds, wid, lane, acc);

        int wm = wid >> 1, wn = wid & 1;
        short* dst = VWt + (size_t)b * NH * 1024 + h * 512;
#pragma unroll
        for (int i = 0; i < 4; ++i)
#pragma unroll
            for (int j = 0; j < 4; ++j) {
                int col = nt * 128 + wn * 64 + j * 16 + l15;     // s
                int row0 = mt * 128 + wm * 64 + i * 16 + crow;   // o
#pragma unroll
                for (int r = 0; r < 4; ++r)
                    dst[(size_t)(row0 + r) * 1024 + col] = f2b(acc[i][j][r]);
            }
    } else {
        // scores staged: S_bf[b][h][e][s] = EXP(q . K). 64 blocks, 64x128.
        int l = swz8(t - 256, 8);
        int b = l >> 3, h = (l >> 2) & 1, st = l & 3;

        const short* Ag = q_bf + h * DH;
        const short* Bg = K_bf + (size_t)(b * SL + st * 128) * NH + h * DH;

        f32x4 acc[4][2];
#pragma unroll
        for (int i = 0; i < 4; ++i)
#pragma unroll
            for (int j = 0; j < 2; ++j) acc[i][j] = (f32x4)0.f;

        m97_core64(Ag, NH, Bg, NH, DH, Alds, Blds, wid, lane, acc);

#pragma unroll
        for (int i = 0; i < 4; ++i)
#pragma unroll
            for (int j = 0; j < 2; ++j) {
                int col = st * 128 + wid * 32 + j * 16 + l15;
#pragma unroll
                for (int r = 0; r < 4; ++r) {
                    int row = i * 16 + crow + r;
                    S_bf[(((size_t)(b * HEADS + h)) * NE + row) * SL + col] = f2b(__expf(acc[i][j][r]));
                }
            }
    }
}

// ---------------------------------------------------------------------------
// pnorm: P[(b*16+ent)*64+e][h*512+s] = mask ? expS*inv : 0. grid 256.
__global__ void __launch_bounds__(256, 4)
pnorm_kernel(const short* __restrict__ S_bf,
             const void* __restrict__ ents,
             const int* __restrict__ flag,
             short* __restrict__ P) {
    int l = swz8(blockIdx.x, 32); // b*32 + ent*2 + eh
    int b = l >> 5, ent = (l >> 1) & 15, eh = l & 1;
    int tid = threadIdx.x, lane = tid & 63, wid = tid >> 6;

    unsigned att8 = 0;
    {
        size_t mbase = ((size_t)b * EN + ent) * SL + lane * 8;
        if (flag[0]) {
            const int* p = (const int*)ents;
#pragma unroll
            for (int j = 0; j < 8; ++j)
                if (p[mbase + j]) att8 |= 1u << j;
        } else {
            const unsigned char* p = (const unsigned char*)ents;
#pragma unroll
            for (int j = 0; j < 8; ++j)
                if (p[mbase + j]) att8 |= 1u << j;
        }
    }

    for (int it = 0; it < 8; ++it) {
        int e = eh * 32 + wid * 8 + it;
        const short* s0p = S_bf + (((size_t)(b * HEADS + 0)) * NE + e) * SL + lane * 8;
        const short* s1p = S_bf + (((size_t)(b * HEADS + 1)) * NE + e) * SL + lane * 8;
        short8 v0 = *(const short8*)s0p;
        short8 v1 = *(const short8*)s1p;
        float f0[8], f1[8], sum0 = 0.f, sum1 = 0.f;
#pragma unroll
        for (int j = 0; j < 8; ++j) {
            f0[j] = (att8 >> j & 1) ? b2f(v0[j]) : 0.f;
            f1[j] = (att8 >> j & 1) ? b2f(v1[j]) : 0.f;
            sum0 += f0[j];
            sum1 += f1[j];
        }
#pragma unroll
        for (int off = 32; off; off >>= 1) {
            sum0 += __shfl_xor(sum0, off);
            sum1 += __shfl_xor(sum1, off);
        }
        float iv0 = 1.f / sum0, iv1 = 1.f / sum1;
        short8 o0, o1;
#pragma unroll
        for (int j = 0; j < 8; ++j) {
            o0[j] = f2b(f0[j] * iv0);
            o1[j] = f2b(f1[j] * iv1);
        }
        short* prow = P + ((size_t)(b * EN + ent) * NE + e) * 1024;
        *(short8*)(prow + lane * 8) = o0;
        *(short8*)(prow + 512 + lane * 8) = o1;
    }
}

// ---------------------------------------------------------------------------
// outg: out = P @ VWt2^T + bo. M=8192, N=512, K=1024. 128x64 tiles, grid 512
// (2 blocks/CU co-resident; 48 KB LDS).
__global__ void __launch_bounds__(256, 2)
outg(const short* __restrict__ P,
     const short* __restrict__ VWt,
     const float* __restrict__ bo,
     float* __restrict__ out) {
    __shared__ short Alds[2 * 128 * 64]; // 32 KB
    __shared__ short Blds[2 * 64 * 64];  // 16 KB
    int l = swz8(blockIdx.x, 64); // b*64 + mt*8 + nt
    int b = l >> 6, mt = (l >> 3) & 7, nt = l & 7;
    int tid = threadIdx.x, lane = tid & 63, wid = tid >> 6;
    int l15 = lane & 15;
    int crow = (lane >> 4) * 4;

    const short* Ag = P + ((size_t)b * 1024 + mt * 128) * 1024;
    const short* Bg = VWt + ((size_t)b * NH + nt * 64) * 1024;

    f32x4 acc[4][2];
#pragma unroll
    for (int i = 0; i < 4; ++i)
#pragma unroll
        for (int j = 0; j < 2; ++j) acc[i][j] = (f32x4)0.f;

    m97_core128x64(Ag, 1024, Bg, 1024, 1024, Alds, Blds, wid, lane, acc);

    int wm = wid >> 1, wn = wid & 1;
    int gr0 = b * 1024 + mt * 128 + wm * 64;
#pragma unroll
    for (int i = 0; i < 4; ++i)
#pragma unroll
        for (int j = 0; j < 2; ++j) {
            int col = nt * 64 + wn * 32 + j * 16 + l15;
            float bval = bo[col];
#pragma unroll
            for (int r = 0; r < 4; ++r) {
                int row = gr0 + i * 16 + crow + r;
                out[(size_t)row * NH + col] = acc[i][j][r] + bval;
            }
        }
}

// ---------------------------------------------------------------------------
extern "C" void kernel_launch(void* const* d_in, const int* in_sizes, int n_in,
                              void* d_out, int out_size, void* d_ws, size_t ws_size,
                              hipStream_t stream) {
    const float* toks = (const float*)d_in[0];
    const void* ents = d_in[1];
    const float* evs = (const float*)d_in[2];
    const float* Wq = (const float*)d_in[6];
    const float* Wk = (const float*)d_in[7];
    const float* Wv = (const float*)d_in[8];
    const float* bq = (const float*)d_in[9];
    const float* bk = (const float*)d_in[10];
    const float* bv = (const float*)d_in[11];
    const float* Wo = (const float*)d_in[12];
    const float* bo = (const float*)d_in[13];

    char* ws = (char*)d_ws;
    short* toks_bf = (short*)(ws + WS_TOKS);
    short* K_bf = (short*)(ws + WS_K);
    short* V_bf = (short*)(ws + WS_V);
    short* S_bf = (short*)(ws + WS_S);
    short* Wk_bf = (short*)(ws + WS_WK);
    short* Wv_bf = (short*)(ws + WS_WV);
    short* Wo_bf = (short*)(ws + WS_WO);
    short* Wq_bf = (short*)(ws + WS_WQ);
    short* ev_bf = (short*)(ws + WS_EV);
    short* q_bf = (short*)(ws + WS_Q);
    int* flag = (int*)(ws + WS_FLAG);
    short* VWt = (short*)(ws + WS_VW);
    short* P = (short*)(ws + WS_P);

    prep_kernel<<<CH_TOTAL / 256 + 1, 256, 0, stream>>>(
        toks, Wk, Wv, Wo, Wq, evs, (const unsigned char*)ents,
        toks_bf, Wk_bf, Wv_bf, Wo_bf, Wq_bf, ev_bf, flag);
    projn<<<260, 256, 0, stream>>>(toks_bf, Wk_bf, Wv_bf, ev_bf, Wq_bf,
                                   bk, bv, bq, K_bf, V_bf, q_bf);
    vwtn_scores<<<320, 256, 0, stream>>>(V_bf, Wo_bf, q_bf, K_bf, VWt, S_bf);
    pnorm_kernel<<<256, 256, 0, stream>>>(S_bf, ents, flag, P);
    outg<<<512, 256, 0, stream>>>(P, VWt, bo, (float*)d_out);
}